// Round 7
// baseline (376.326 us; speedup 1.0000x reference)
//
#include <hip/hip_runtime.h>
#include <hip/hip_bf16.h>
#include <math.h>

// Problem constants
#define BS 32
#define TT 512
#define HH 1024
#define NH 16
#define DH 64
#define MM (BS*TT)          // 16384 rows
#define NCAT 2176           // 1024(Q) + 1024(K) + 64(V) + 64(pad)

typedef __attribute__((ext_vector_type(8))) __bf16 bf16x8;
typedef __attribute__((ext_vector_type(4))) float  f32x4;

#define QSCALE 0.18033688011112042f   // dh^-0.5 * log2(e) -> softmax in exp2 domain

// Native 2^x (single v_exp_f32); confirmed R5: halved VALUBusy.
#if __has_builtin(__builtin_amdgcn_exp2f)
#define EXP2F(x) __builtin_amdgcn_exp2f(x)
#else
#define EXP2F(x) __expf((x) * 0.69314718055994531f)
#endif

// async global->LDS, 16B per lane, LDS dest = wave-uniform base + lane*16
__device__ __forceinline__ void gld16(const void* g, void* l) {
    __builtin_amdgcn_global_load_lds(
        (const __attribute__((address_space(1))) unsigned int*)g,
        (__attribute__((address_space(3))) unsigned int*)l,
        16, 0, 0);
}

// ---------------------------------------------------------------------------
// Prep 1: x fp32 -> bf16 (row-major [M][K] unchanged)
// ---------------------------------------------------------------------------
__global__ __launch_bounds__(256) void cvt_x(const float* __restrict__ x,
                                             __bf16* __restrict__ xb)
{
    const size_t i = ((size_t)blockIdx.x * 256 + threadIdx.x) * 8;
    float4 a = *(const float4*)(x + i);
    float4 b = *(const float4*)(x + i + 4);
    bf16x8 v;
    v[0] = (__bf16)a.x; v[1] = (__bf16)a.y; v[2] = (__bf16)a.z; v[3] = (__bf16)a.w;
    v[4] = (__bf16)b.x; v[5] = (__bf16)b.y; v[6] = (__bf16)b.z; v[7] = (__bf16)b.w;
    *(bf16x8*)(xb + i) = v;
}

// ---------------------------------------------------------------------------
// Prep 2: Wt[n][k] bf16 = concat(Wq,Wk,Wv,0)^T; bias_cat[n] fp32.
// ---------------------------------------------------------------------------
__global__ __launch_bounds__(256) void prep_w(
    const float* __restrict__ Wq, const float* __restrict__ Wk,
    const float* __restrict__ Wv, const float* __restrict__ bq_,
    const float* __restrict__ bk_, const float* __restrict__ bv_,
    __bf16* __restrict__ Wt, float* __restrict__ bias_cat)
{
    __shared__ __align__(16) __bf16 tile[64][72];
    const int tid = threadIdx.x;
    const int n0 = blockIdx.x * 64;
    const int k0 = blockIdx.y * 64;

    const int n_l = tid & 63;
    const int k_b = tid >> 6;
    const int n   = n0 + n_l;
    #pragma unroll
    for (int j = 0; j < 16; ++j) {
        const int k_l = j * 4 + k_b;
        const int k   = k0 + k_l;
        float v;
        if (n < 1024)      v = Wq[(size_t)k * 1024 + n];
        else if (n < 2048) v = Wk[(size_t)k * 1024 + (n - 1024)];
        else if (n < 2112) v = Wv[(size_t)k * 64 + (n - 2048)];
        else               v = 0.f;
        tile[n_l][k_l] = (__bf16)v;
    }
    if (blockIdx.y == 0 && tid < 64) {
        const int nn = n0 + tid;
        bias_cat[nn] = (nn < 1024) ? bq_[nn]
                     : (nn < 2048) ? bk_[nn - 1024]
                     : (nn < 2112) ? bv_[nn - 2048] : 0.f;
    }
    __syncthreads();
    const int n_l2 = tid >> 2;
    const int k_l2 = (tid & 3) * 16;
    __bf16* dst = Wt + (size_t)(n0 + n_l2) * 1024 + k0 + k_l2;
    *(bf16x8*)dst       = *(const bf16x8*)&tile[n_l2][k_l2];
    *(bf16x8*)(dst + 8) = *(const bf16x8*)&tile[n_l2][k_l2 + 8];
}

// ---------------------------------------------------------------------------
// Prep 3: WoT[n][k] bf16 = Wo[k][n]^T  (64x1024 fp32 -> 1024x64 bf16)
// ---------------------------------------------------------------------------
__global__ __launch_bounds__(256) void prep_wo(const float* __restrict__ Wo,
                                               __bf16* __restrict__ WoT)
{
    const int idx = blockIdx.x * 256 + threadIdx.x;   // over 1024*8
    const int n  = idx >> 3;
    const int k0 = (idx & 7) * 8;
    bf16x8 v;
    #pragma unroll
    for (int j = 0; j < 8; ++j) v[j] = (__bf16)Wo[(size_t)(k0 + j) * 1024 + n];
    *(bf16x8*)(WoT + (size_t)n * 64 + k0) = v;
}

// ---------------------------------------------------------------------------
// Fused QKV GEMM v7: 128x128 tile, BK=64, double-buffered LDS, ONE
// __syncthreads per K-step (prefetch-overlapped "minimum 2-phase"):
//   iter t: issue gld16(tile t+1 -> buf^1); ds_read+32 MFMA on buf; sync.
// 16 K-steps x 1 barrier (was 32 x 2) and loads fly under ~1240cyc of MFMA.
// LDS reads XOR-swizzled by (row&7) on 16B groups (T21: linear LDS dest,
// pre-swizzled global source, swizzled read -> 8 dwords/bank minimum; R6
// showed 8.9M bank conflicts = 2x LDS cycles on the read path).
// Bijective XCD-aware block swizzle kept (nwg=2176=8*272).
// ---------------------------------------------------------------------------
__global__ __launch_bounds__(256) void gemm_qkv(
    const __bf16* __restrict__ A, const __bf16* __restrict__ B,
    const float* __restrict__ bias_cat,
    __bf16* __restrict__ Qo, __bf16* __restrict__ Ko,
    __bf16* __restrict__ Vt)
{
    __shared__ __align__(16) __bf16 sA[2][128 * 64];   // 32 KB
    __shared__ __align__(16) __bf16 sB[2][128 * 64];   // 32 KB

    const int tid  = threadIdx.x;
    const int wv   = tid >> 6;
    const int ln   = tid & 63;
    const int quad = ln >> 4;
    const int l16  = ln & 15;

    // XCD swizzle: grid = dim3(17,128) -> 2176 blocks, 2176 % 8 == 0
    const int orig = blockIdx.y * 17 + blockIdx.x;
    const int swz  = (orig & 7) * 272 + (orig >> 3);
    const int m0 = (swz / 17) * 128;
    const int n0 = (swz % 17) * 128;

    const int rw = (wv & 1) * 64;    // wave row quadrant
    const int cw = (wv >> 1) * 64;   // wave col quadrant

    f32x4 acc[4][4];
    #pragma unroll
    for (int i = 0; i < 4; ++i)
        #pragma unroll
        for (int j = 0; j < 4; ++j) acc[i][j] = f32x4{0, 0, 0, 0};

    // staging: wave wv stages rows [wv*32 + r*8 .. +7] of both tiles.
    // source 16B-group = (ln&7) ^ (row&7) = (ln&7) ^ ((ln>>3)&7)  [T21]
    const int srow8 = ln >> 3;                 // row within 8-row chunk
    const int srcg  = (ln & 7) ^ (srow8 & 7);  // pre-swizzled source group
    const int swr   = (l16 & 7);               // read-side row&7

    // prologue: stage tile 0 into buf 0
    #pragma unroll
    for (int r = 0; r < 4; ++r) {
        const int rowb = wv * 32 + r * 8;
        gld16(A + (size_t)(m0 + rowb + srow8) * 1024 + srcg * 8, &sA[0][rowb * 64]);
        gld16(B + (size_t)(n0 + rowb + srow8) * 1024 + srcg * 8, &sB[0][rowb * 64]);
    }
    __syncthreads();

    int p = 0;
    for (int k0 = 0; k0 < 1024; k0 += 64) {
        if (k0 + 64 < 1024) {
            #pragma unroll
            for (int r = 0; r < 4; ++r) {
                const int rowb = wv * 32 + r * 8;
                gld16(A + (size_t)(m0 + rowb + srow8) * 1024 + k0 + 64 + srcg * 8,
                      &sA[p ^ 1][rowb * 64]);
                gld16(B + (size_t)(n0 + rowb + srow8) * 1024 + k0 + 64 + srcg * 8,
                      &sB[p ^ 1][rowb * 64]);
            }
        }
        __builtin_amdgcn_sched_barrier(0);   // pin load issue before compute

        const __bf16* la = sA[p];
        const __bf16* lb = sB[p];
        #pragma unroll
        for (int ks = 0; ks < 2; ++ks) {
            const int pg = ((ks * 4 + quad) ^ swr) * 8;   // swizzled group
            bf16x8 af[4], bfr[4];
            #pragma unroll
            for (int mt = 0; mt < 4; ++mt)
                af[mt] = *(const bf16x8*)&la[(rw + mt * 16 + l16) * 64 + pg];
            #pragma unroll
            for (int nt = 0; nt < 4; ++nt)
                bfr[nt] = *(const bf16x8*)&lb[(cw + nt * 16 + l16) * 64 + pg];
            #pragma unroll
            for (int mt = 0; mt < 4; ++mt)
                #pragma unroll
                for (int nt = 0; nt < 4; ++nt)
                    acc[mt][nt] = __builtin_amdgcn_mfma_f32_16x16x32_bf16(af[mt], bfr[nt], acc[mt][nt], 0, 0, 0);
        }
        __syncthreads();   // drains vmcnt (next tile staged) + lgkmcnt
        p ^= 1;
    }

    #pragma unroll
    for (int mt = 0; mt < 4; ++mt) {
        #pragma unroll
        for (int nt = 0; nt < 4; ++nt) {
            const int colb = n0 + cw + nt * 16 + l16;
            if (colb >= 2112) continue;
            const float bias = bias_cat[colb];
            #pragma unroll
            for (int r = 0; r < 4; ++r) {
                const int row = m0 + rw + mt * 16 + quad * 4 + r;
                const int b = row >> 9, t = row & 511;
                float v = acc[mt][nt][r] + bias;
                if (colb < 1024) {
                    const int h = colb >> 6, d = colb & 63;
                    Qo[(((size_t)(b * NH + h) * TT) + t) * DH + d] = (__bf16)(v * QSCALE);
                } else if (colb < 2048) {
                    const int c = colb - 1024;
                    const int h = c >> 6, d = c & 63;
                    Ko[(((size_t)(b * NH + h) * TT) + t) * DH + d] = (__bf16)v;
                } else {
                    const int d = colb - 2048;
                    Vt[((size_t)(b * DH + d)) * TT + t] = (__bf16)v;
                }
            }
        }
    }
}

// ---------------------------------------------------------------------------
// MFMA flash attention, v6 (unchanged — R6 confirmed): block = ONE HEAD,
// 16 waves = 16 q-tiles; K+V staged once in LDS (XOR-swizzled, T21);
// k-loop 100% LDS/compute; SIMD-balanced qt2 map; EXP2F softmax.
// ---------------------------------------------------------------------------
__global__ __launch_bounds__(1024) void attn_mfma(
    const __bf16* __restrict__ Q, const __bf16* __restrict__ K,
    const __bf16* __restrict__ Vt, float* __restrict__ attn_vec)
{
    __shared__ __align__(16) __bf16 sK[512 * 64];   // 64 KB [t][d], 16B groups XOR-swizzled by swzK(t)
    __shared__ __align__(16) __bf16 sV[64][512];    // 64 KB [d][t], 16B groups XOR-swizzled by (d&7)

    const int bh   = blockIdx.x;           // b*NH + h
    const int b    = bh >> 4;
    const int wave = threadIdx.x >> 6;
    const int lane = threadIdx.x & 63;
    const int quad = lane >> 4;
    const int l16  = lane & 15;

    // SIMD-balanced qt2 assignment: SIMD s = wave&3 hosts qt2 {s,7-s,8+s,15-s}
    const int s_ = wave & 3, j_ = wave >> 2;
    const int qt2 = (j_ == 0) ? s_ : (j_ == 1) ? (7 - s_) : (j_ == 2) ? (8 + s_) : (15 - s_);
    const int q0   = qt2 << 5;
    const int kend = q0 + 32;

    const __bf16* Qbh = Q + (size_t)bh * TT * DH;
    const __bf16* Kbh = K + (size_t)bh * TT * DH;
    const __bf16* Vb  = Vt + (size_t)b * DH * TT;

    // ---- stage K: wave w stages row-chunks c = w*4+r (8 rows each).
    #pragma unroll
    for (int r = 0; r < 4; ++r) {
        const int c   = wave * 4 + r;
        const int row = c * 8 + (lane >> 3);
        const int pp  = lane & 7;
        const int swzr = (row & 3) | (((row >> 3) & 1) << 2);
        gld16(Kbh + (size_t)row * DH + ((pp ^ swzr) * 8), sK + (size_t)c * 512);
    }
    // ---- stage V: wave w stages rows w, w+16, w+32, w+48 (row&7 = w&7).
    const int svw = wave & 7;
    #pragma unroll
    for (int r = 0; r < 4; ++r) {
        const int row = wave + r * 16;
        gld16(Vb + (size_t)row * TT + ((lane ^ svw) * 8), &sV[row][0]);
    }

    // Q fragments for this wave's 32-query tile (global, once)
    const bf16x8 qA_lo = *(const bf16x8*)(Qbh + (size_t)(q0 + l16) * DH + quad * 8);
    const bf16x8 qA_hi = *(const bf16x8*)(Qbh + (size_t)(q0 + l16) * DH + 32 + quad * 8);
    const bf16x8 qB_lo = *(const bf16x8*)(Qbh + (size_t)(q0 + 16 + l16) * DH + quad * 8);
    const bf16x8 qB_hi = *(const bf16x8*)(Qbh + (size_t)(q0 + 16 + l16) * DH + 32 + quad * 8);

    // permuted K row: sigma1(l16) = (l16>>2)*8 + (l16&3); sigma2 = +4.
    const int perm = ((l16 >> 2) << 3) + (l16 & 3);
    const int swzl = (l16 & 3) | (((l16 >> 2) & 1) << 2);
    const __bf16* k1lo = sK + (size_t)perm * DH       + (( quad      ^ swzl) * 8);
    const __bf16* k1hi = sK + (size_t)perm * DH       + (((quad | 4) ^ swzl) * 8);
    const __bf16* k2lo = sK + (size_t)(perm + 4) * DH + (( quad      ^ swzl) * 8);
    const __bf16* k2hi = sK + (size_t)(perm + 4) * DH + (((quad | 4) ^ swzl) * 8);

    const int sx = l16 & 7;   // V read swizzle

    f32x4 OA[4] = {f32x4{0,0,0,0}, f32x4{0,0,0,0}, f32x4{0,0,0,0}, f32x4{0,0,0,0}};
    f32x4 OB[4] = {f32x4{0,0,0,0}, f32x4{0,0,0,0}, f32x4{0,0,0,0}, f32x4{0,0,0,0}};
    float lA = 0.f, lB = 0.f;     // per-lane partial denominators

    __syncthreads();   // K+V staged (compiler drains vmcnt before s_barrier)

    for (int kb0 = 0; kb0 < kend; kb0 += 32) {
        const int ko = kb0 * DH;   // element offset of this K block
        bf16x8 c1a = *(const bf16x8*)(k1lo + ko);
        bf16x8 c1b = *(const bf16x8*)(k1hi + ko);
        bf16x8 c2a = *(const bf16x8*)(k2lo + ko);
        bf16x8 c2b = *(const bf16x8*)(k2hi + ko);

        // V fragments: logical group (kb0>>3)+quad -> physical ^sx
        const int vg = (((kb0 >> 3) + quad) ^ sx) * 8;
        bf16x8 vf0 = *(const bf16x8*)&sV[l16][vg];
        bf16x8 vf1 = *(const bf16x8*)&sV[16 + l16][vg];
        bf16x8 vf2 = *(const bf16x8*)&sV[32 + l16][vg];
        bf16x8 vf3 = *(const bf16x8*)&sV[48 + l16][vg];

        f32x4 s1A = __builtin_amdgcn_mfma_f32_16x16x32_bf16(c1a, qA_lo, f32x4{0,0,0,0}, 0, 0, 0);
        s1A       = __builtin_amdgcn_mfma_f32_16x16x32_bf16(c1b, qA_hi, s1A, 0, 0, 0);
        f32x4 s2A = __builtin_amdgcn_mfma_f32_16x16x32_bf16(c2a, qA_lo, f32x4{0,0,0,0}, 0, 0, 0);
        s2A       = __builtin_amdgcn_mfma_f32_16x16x32_bf16(c2b, qA_hi, s2A, 0, 0, 0);
        f32x4 s1B = __builtin_amdgcn_mfma_f32_16x16x32_bf16(c1a, qB_lo, f32x4{0,0,0,0}, 0, 0, 0);
        s1B       = __builtin_amdgcn_mfma_f32_16x16x32_bf16(c1b, qB_hi, s1B, 0, 0, 0);
        f32x4 s2B = __builtin_amdgcn_mfma_f32_16x16x32_bf16(c2a, qB_lo, f32x4{0,0,0,0}, 0, 0, 0);
        s2B       = __builtin_amdgcn_mfma_f32_16x16x32_bf16(c2b, qB_hi, s2B, 0, 0, 0);

        if (kb0 == q0) {   // only the diagonal block needs masking
            const int qqA = q0 + l16, qqB = q0 + 16 + l16;
            #pragma unroll
            for (int r = 0; r < 4; ++r) {
                const int key1 = kb0 + quad * 8 + r;
                const int key2 = key1 + 4;
                if (key1 > qqA) s1A[r] = -INFINITY;
                if (key2 > qqA) s2A[r] = -INFINITY;
                if (key1 > qqB) s1B[r] = -INFINITY;
                if (key2 > qqB) s2B[r] = -INFINITY;
            }
        }

        // p = exp2(s) via native v_exp_f32; accumulate per-lane denominator
        bf16x8 pfA, pfB;
        float psA0 = 0.f, psA1 = 0.f, psB0 = 0.f, psB1 = 0.f;
        #pragma unroll
        for (int r = 0; r < 4; ++r) {
            float pa0 = EXP2F(s1A[r]);
            float pa1 = EXP2F(s2A[r]);
            float pb0 = EXP2F(s1B[r]);
            float pb1 = EXP2F(s2B[r]);
            psA0 += pa0; psA1 += pa1;
            psB0 += pb0; psB1 += pb1;
            pfA[r]     = (__bf16)pa0;
            pfA[4 + r] = (__bf16)pa1;
            pfB[r]     = (__bf16)pb0;
            pfB[4 + r] = (__bf16)pb1;
        }
        lA += psA0 + psA1;
        lB += psB0 + psB1;

        OA[0] = __builtin_amdgcn_mfma_f32_16x16x32_bf16(pfA, vf0, OA[0], 0, 0, 0);
        OB[0] = __builtin_amdgcn_mfma_f32_16x16x32_bf16(pfB, vf0, OB[0], 0, 0, 0);
        OA[1] = __builtin_amdgcn_mfma_f32_16x16x32_bf16(pfA, vf1, OA[1], 0, 0, 0);
        OB[1] = __builtin_amdgcn_mfma_f32_16x16x32_bf16(pfB, vf1, OB[1], 0, 0, 0);
        OA[2] = __builtin_amdgcn_mfma_f32_16x16x32_bf16(pfA, vf2, OA[2], 0, 0, 0);
        OB[2] = __builtin_amdgcn_mfma_f32_16x16x32_bf16(pfB, vf2, OB[2], 0, 0, 0);
        OA[3] = __builtin_amdgcn_mfma_f32_16x16x32_bf16(pfA, vf3, OA[3], 0, 0, 0);
        OB[3] = __builtin_amdgcn_mfma_f32_16x16x32_bf16(pfB, vf3, OB[3], 0, 0, 0);
    }

    // reduce denominators across quads
    lA += __shfl_xor(lA, 16);
    lA += __shfl_xor(lA, 32);
    lB += __shfl_xor(lB, 16);
    lB += __shfl_xor(lB, 32);

    #pragma unroll
    for (int r = 0; r < 4; ++r) {
        const float invA = 1.0f / __shfl(lA, quad * 4 + r);
        const float invB = 1.0f / __shfl(lB, quad * 4 + r);
        const int tA = q0 + quad * 4 + r;
        const int tB = tA + 16;
        float* opA = attn_vec + ((size_t)bh * TT + tA) * DH + l16;
        float* opB = attn_vec + ((size_t)bh * TT + tB) * DH + l16;
        #pragma unroll
        for (int nt = 0; nt < 4; ++nt) {
            opA[nt * 16] = OA[nt][r] * invA;
            opB[nt * 16] = OB[nt][r] * invB;
        }
    }
}

// ---------------------------------------------------------------------------
// Head-mean -> bf16: mavb[b*TT+t][d] = (1/16) sum_h av[b,h,t,d]
// ---------------------------------------------------------------------------
__global__ __launch_bounds__(256) void reduce_heads(
    const float* __restrict__ av, __bf16* __restrict__ mavb)
{
    const size_t idx = (size_t)blockIdx.x * 256 + threadIdx.x;  // over MM*8
    const int    d8  = (int)(idx & 7) * 8;
    const size_t bt  = idx >> 3;                   // b*TT + t
    const int    b   = (int)(bt >> 9);
    const int    t   = (int)(bt & 511);
    const float4* p = (const float4*)av + ((size_t)b * NH * TT + t) * 16 + (d8 >> 2);
    float4 a0 = p[0], a1 = p[1];
    #pragma unroll
    for (int h = 1; h < NH; ++h) {
        const float4* q = p + (size_t)h * TT * 16;
        float4 v0 = q[0], v1 = q[1];
        a0.x += v0.x; a0.y += v0.y; a0.z += v0.z; a0.w += v0.w;
        a1.x += v1.x; a1.y += v1.y; a1.z += v1.z; a1.w += v1.w;
    }
    bf16x8 o;
    o[0] = (__bf16)(a0.x * (1.f/16.f)); o[1] = (__bf16)(a0.y * (1.f/16.f));
    o[2] = (__bf16)(a0.z * (1.f/16.f)); o[3] = (__bf16)(a0.w * (1.f/16.f));
    o[4] = (__bf16)(a1.x * (1.f/16.f)); o[5] = (__bf16)(a1.y * (1.f/16.f));
    o[6] = (__bf16)(a1.z * (1.f/16.f)); o[7] = (__bf16)(a1.w * (1.f/16.f));
    *(bf16x8*)(mavb + bt * DH + d8) = o;
}

// ---------------------------------------------------------------------------
// Out-proj GEMM v2, LDS-free: out[M,1024] = mavb[M,64] @ WoT^T.
// A (mavb, 2MB) and B (WoT, 128KB) are L2-hot; frags read direct-from-global.
// Block = 256 rows x 64 cols; wave wv owns rows wv*64..+63 (4x4 frags, ks=2).
// Floor = the 67MB C-write.
// ---------------------------------------------------------------------------
__global__ __launch_bounds__(256) void gemm_out(
    const __bf16* __restrict__ A, const __bf16* __restrict__ Bt,
    float* __restrict__ C)
{
    const int tid  = threadIdx.x;
    const int wv   = tid >> 6;
    const int ln   = tid & 63;
    const int quad = ln >> 4;
    const int l16  = ln & 15;
    const int n0 = blockIdx.x * 64;
    const int m0 = blockIdx.y * 256 + wv * 64;

    f32x4 acc[4][4];
    #pragma unroll
    for (int i = 0; i < 4; ++i)
        #pragma unroll
        for (int j = 0; j < 4; ++j) acc[i][j] = f32x4{0, 0, 0, 0};

    #pragma unroll
    for (int ks = 0; ks < 2; ++ks) {
        const int kofs = ks * 32 + quad * 8;
        bf16x8 bfr[4];
        #pragma unroll
        for (int nt = 0; nt < 4; ++nt)
            bfr[nt] = *(const bf16x8*)&Bt[(size_t)(n0 + nt * 16 + l16) * 64 + kofs];
        #pragma unroll
        for (int mt = 0; mt < 4; ++mt) {
            bf16x8 af = *(const bf16x8*)&A[(size_t)(m0 + mt * 16 + l16) * 64 + kofs];
            #pragma unroll
            for (int nt = 0; nt < 4; ++nt)
                acc[mt][nt] = __builtin_amdgcn_mfma_f32_16x16x32_bf16(af, bfr[nt], acc[mt][nt], 0, 0, 0);
        }
    }

    #pragma unroll
    for (int mt = 0; mt < 4; ++mt) {
        #pragma unroll
        for (int nt = 0; nt < 4; ++nt) {
            #pragma unroll
            for (int r = 0; r < 4; ++r) {
                const int row = m0 + mt * 16 + quad * 4 + r;
                const int col = n0 + nt * 16 + l16;
                C[(size_t)row * HH + col] = acc[mt][nt][r];
            }
        }
    }
}

// ---------------------------------------------------------------------------
extern "C" void kernel_launch(void* const* d_in, const int* in_sizes, int n_in,
                              void* d_out, int out_size, void* d_ws, size_t ws_size,
                              hipStream_t stream)
{
    const float* x  = (const float*)d_in[0];
    const float* Wq = (const float*)d_in[1];
    const float* bq = (const float*)d_in[2];
    const float* Wk = (const float*)d_in[3];
    const float* bk = (const float*)d_in[4];
    const float* Wv = (const float*)d_in[5];
    const float* bv = (const float*)d_in[6];
    const float* Wo = (const float*)d_in[7];

    float* out      = (float*)d_out;                       // [32,512,1024]
    float* attn_vec = out + (size_t)MM * HH;               // [32,16,512,64]

    char* ws = (char*)d_ws;
    __bf16* xb  = (__bf16*)ws;                              // [M][1024]    33.5 MB
    __bf16* Wt  = xb + (size_t)MM * HH;                     // [2176][1024]  4.45 MB
    float* bias_cat = (float*)(Wt + (size_t)NCAT * HH);     // 2176 (pad 2304)
    __bf16* Qb  = (__bf16*)(bias_cat + 2304);               // [b,h,t,d]    33.5 MB
    __bf16* Kb  = Qb + (size_t)MM * HH;                     // [b,h,t,d]    33.5 MB
    __bf16* Vt  = Kb + (size_t)MM * HH;                     // [b,d,t]       2.1 MB
    __bf16* WoT = Vt + (size_t)BS * DH * TT;                // [1024][64]    128 KB
    __bf16* mavb = xb;   // alias: xb dead after gemm_qkv; written by reduce_heads

    cvt_x<<<MM * HH / (256 * 8), 256, 0, stream>>>(x, xb);
    prep_w<<<dim3(NCAT / 64, HH / 64), 256, 0, stream>>>(Wq, Wk, Wv, bq, bk, bv, Wt, bias_cat);
    prep_wo<<<(HH * 8) / 256, 256, 0, stream>>>(Wo, WoT);
    gemm_qkv<<<dim3(NCAT / 128, MM / 128), 256, 0, stream>>>(xb, Wt, bias_cat, Qb, Kb, Vt);
    attn_mfma<<<BS * NH, 1024, 0, stream>>>(Qb, Kb, Vt, attn_vec);
    reduce_heads<<<(MM * 8) / 256, 256, 0, stream>>>(attn_vec, mavb);
    gemm_out<<<dim3(HH / 64, MM / 256), 256, 0, stream>>>(mavb, WoT, out);
}